// Round 9
// baseline (492.381 us; speedup 1.0000x reference)
//
#include <hip/hip_runtime.h>
#include <hip/hip_bf16.h>

typedef unsigned short u16;
typedef unsigned long long u64;
typedef __attribute__((ext_vector_type(8))) short bf16x8;
typedef __attribute__((ext_vector_type(4))) float f32x4;

static __device__ __forceinline__ u16 f2bf(float f) {
    union { float f; unsigned u; } cv; cv.f = f;
    unsigned u = cv.u;
    unsigned r = u + 0x7FFF + ((u >> 16) & 1);   // round-to-nearest-even
    return (u16)(r >> 16);
}
static __device__ __forceinline__ float bf2f(u16 b) {
    union { unsigned u; float f; } cv; cv.u = ((unsigned)b) << 16;
    return cv.f;
}
static __device__ __forceinline__ float sigmoidf_(float x) {
    return 1.0f / (1.0f + __expf(-x));
}

// ---------------------------------------------------------------------------
// Fuse Wf = wv @ wo (bf16, stored transposed [j][i]) and bfv = bv@wo + bo.
__global__ __launch_bounds__(256) void fuse_wvwo(
    const float* __restrict__ wv, const float* __restrict__ wo,
    const float* __restrict__ bv, const float* __restrict__ bo,
    u16* __restrict__ WfT, float* __restrict__ bfv)
{
    int j = blockIdx.x;
    int i = threadIdx.x;
    float s = 0.f;
    for (int k = 0; k < 256; ++k) s += wv[i * 256 + k] * wo[k * 256 + j];
    WfT[j * 256 + i] = f2bf(s);
    if (i == 0) {
        float t = bo[j];
        for (int k = 0; k < 256; ++k) t += bv[k] * wo[k * 256 + j];
        bfv[j] = t;
    }
}

// dst[n*K + k] = bf16(src[k*N + n])
__global__ __launch_bounds__(256) void transpose_bf(
    const float* __restrict__ src, u16* __restrict__ dst, int K, int N)
{
    long i = (long)blockIdx.x * 256 + threadIdx.x;
    if (i >= (long)K * N) return;
    int n = (int)(i / K), k = (int)(i % K);
    dst[i] = f2bf(src[(long)k * N + n]);
}

// ---------------------------------------------------------------------------
// Fused action-encoder + LayerNorm, MFMA version. 64 positions per block.
__global__ __launch_bounds__(256) void ae_ln_mfma(
    const float* __restrict__ action,
    const float* __restrict__ w1, const float* __restrict__ b1,
    const u16* __restrict__ w2T, const float* __restrict__ b2,
    const float* __restrict__ g, const float* __restrict__ be,
    u16* __restrict__ kvbf)
{
    __shared__ u16 lB[256][136];   // w2T staged; reused as f32 [64][261] later
    __shared__ u16 lA[64][136];    // h1 tile bf16
    int tid = threadIdx.x;
    long base = (long)blockIdx.x * 64;

    for (int idx = tid; idx < 256 * 16; idx += 256) {
        int r = idx >> 4, ch = (idx & 15) * 8;
        *(uint4*)&lB[r][ch] = *(const uint4*)&w2T[r * 128 + ch];
    }
    for (int idx = tid; idx < 8192; idx += 256) {
        int r = idx >> 7, k = idx & 127;
        float a0 = action[(base + r) * 2], a1 = action[(base + r) * 2 + 1];
        float v = fmaf(a1, w1[128 + k], fmaf(a0, w1[k], b1[k]));
        lA[r][k] = f2bf(v > 0.f ? v : 0.f);
    }
    __syncthreads();

    int wv = tid >> 6, l = tid & 63;
    int fr = l & 15, fq = l >> 4;
    f32x4 acc[4][4] = {};
#pragma unroll
    for (int ks = 0; ks < 4; ++ks) {
        bf16x8 a[4], b[4];
#pragma unroll
        for (int mi = 0; mi < 4; ++mi) a[mi] = *(bf16x8*)&lA[mi * 16 + fr][ks * 32 + fq * 8];
#pragma unroll
        for (int ni = 0; ni < 4; ++ni) b[ni] = *(bf16x8*)&lB[wv * 64 + ni * 16 + fr][ks * 32 + fq * 8];
#pragma unroll
        for (int mi = 0; mi < 4; ++mi)
#pragma unroll
            for (int ni = 0; ni < 4; ++ni)
                acc[mi][ni] = __builtin_amdgcn_mfma_f32_16x16x32_bf16(a[mi], b[ni], acc[mi][ni], 0, 0, 0);
    }
    __syncthreads();

    float* e = (float*)&lB[0][0];   // [64][261] f32 scratch
#pragma unroll
    for (int mi = 0; mi < 4; ++mi)
#pragma unroll
        for (int ni = 0; ni < 4; ++ni) {
            int col = wv * 64 + ni * 16 + fr;
            float bb = b2[col];
#pragma unroll
            for (int reg = 0; reg < 4; ++reg)
                e[(mi * 16 + fq * 4 + reg) * 261 + col] = acc[mi][ni][reg] + bb;
        }
    __syncthreads();

    int t = tid >> 2, sub = tid & 3;
    float s = 0.f, ss = 0.f;
#pragma unroll
    for (int i = 0; i < 64; ++i) {
        float v = e[t * 261 + sub + i * 4];
        s += v; ss += v * v;
    }
    s += __shfl_xor(s, 1); ss += __shfl_xor(ss, 1);
    s += __shfl_xor(s, 2); ss += __shfl_xor(ss, 2);
    float m = s * (1.f / 256.f);
    float var = ss * (1.f / 256.f) - m * m;
    float rs = rsqrtf(var + 1e-5f);
#pragma unroll
    for (int i8 = 0; i8 < 8; ++i8) {
        u16 pack[8];
#pragma unroll
        for (int j = 0; j < 8; ++j) {
            int col = sub * 64 + i8 * 8 + j;
            float v = (e[t * 261 + col] - m) * rs * g[col] + be[col];
            pack[j] = f2bf(v);
        }
        *(uint4*)&kvbf[(base + t) * 256 + sub * 64 + i8 * 8] = *(uint4*)pack;
    }
}

// ---------------------------------------------------------------------------
// 128x128-tile bf16 GEMM: C = A[M,K] @ BT[N,K]^T (+bias[col]) (+modes)
template <int MODE>
__global__ __launch_bounds__(256) void gemm128(
    const u16* __restrict__ A, const u16* __restrict__ BT,
    const float* __restrict__ bias, const float* __restrict__ resid,
    u16* __restrict__ outBf, float* __restrict__ outF,
    int N, int K)
{
    __shared__ u16 lA[128][40];
    __shared__ u16 lB[128][40];
    int tid = threadIdx.x;
    int bm = blockIdx.x * 128, bn = blockIdx.y * 128;

    f32x4 acc[4][4] = {};
    int w = tid >> 6, l = tid & 63;
    int wr = (w >> 1) * 64, wc = (w & 1) * 64;
    int fr = l & 15, fk = (l >> 4) * 8;

    for (int k0 = 0; k0 < K; k0 += 32) {
#pragma unroll
        for (int i = 0; i < 2; ++i) {
            int idx = tid + i * 256;
            int r = idx >> 2, c8 = (idx & 3) * 8;
            *(uint4*)&lA[r][c8] = *(const uint4*)&A[(long)(bm + r) * K + k0 + c8];
            *(uint4*)&lB[r][c8] = *(const uint4*)&BT[(long)(bn + r) * K + k0 + c8];
        }
        __syncthreads();
        bf16x8 a[4], b[4];
#pragma unroll
        for (int mi = 0; mi < 4; ++mi) a[mi] = *(bf16x8*)&lA[wr + mi * 16 + fr][fk];
#pragma unroll
        for (int ni = 0; ni < 4; ++ni) b[ni] = *(bf16x8*)&lB[wc + ni * 16 + fr][fk];
#pragma unroll
        for (int mi = 0; mi < 4; ++mi)
#pragma unroll
            for (int ni = 0; ni < 4; ++ni)
                acc[mi][ni] = __builtin_amdgcn_mfma_f32_16x16x32_bf16(a[mi], b[ni], acc[mi][ni], 0, 0, 0);
        __syncthreads();
    }

#pragma unroll
    for (int mi = 0; mi < 4; ++mi)
#pragma unroll
        for (int ni = 0; ni < 4; ++ni) {
            int c = bn + wc + ni * 16 + fr;
            float bz = bias[c];
#pragma unroll
            for (int reg = 0; reg < 4; ++reg) {
                int r = bm + wr + mi * 16 + (l >> 4) * 4 + reg;
                float v = acc[mi][ni][reg] + bz;
                if constexpr (MODE == 0) {
                    v += resid[(long)r * N + c];
                    outBf[(long)r * N + c] = f2bf(v);
                } else if constexpr (MODE == 1) {
                    outBf[(long)r * N + c] = f2bf(v);
                } else {
                    outF[(long)r * N + c] = v;
                    if ((r & 511) == 511) outF[8388608 + (long)(r >> 9) * N + c] = v;
                }
            }
        }
}

// ---------------------------------------------------------------------------
// Persistent GRU v7: two-chain antiphase pipeline.
// 256 blocks = 32 pairs x 8 col-blocks (64 cols). Block owns chain A (t-rows
// p*8..p*8+7) and chain B (p*8+256..+263), each an independent recurrence.
// 768 threads = 12 waves = (gate 0..2, cpos 0..3), whh frags in regs (64 VGPR).
// Per superstep: X phase advances A (while B's h-loads/gi-loads are issued and
// settle under A's MFMA+gates), Y phase advances B symmetrically. The
// store->flag->poll->load round trip of each chain hides under the other
// chain's compute. MFMA uses 8 valid B-rows of 16 (duplicated) -- MFMA is not
// the bottleneck. Flags: sense-barrier per chain over the 8 peer blocks.
__global__ __launch_bounds__(768, 1) void gru_persistent7(
    const u16* __restrict__ whhT, const float* __restrict__ bhh,
    const u16* __restrict__ gi_bf, const u16* __restrict__ h0_bf,
    u16* __restrict__ out_bf, unsigned* __restrict__ flagsA,
    unsigned* __restrict__ flagsB)
{
    __shared__ u64 lhA[1024];                      // 8 rows x 512 bf16, swizzled
    __shared__ u64 lhB[1024];
    __shared__ __align__(16) float ghs[3][8][68];  // [gate][t_loc][c_loc]
    u16* lA16 = (u16*)lhA;
    u16* lB16 = (u16*)lhB;

    int tid = threadIdx.x, bid = blockIdx.x;
    int p = bid >> 3, cb = bid & 7;
    int tA = p * 8, tB = tA + 256;
    int cbase = cb * 64;

    int w = tid >> 6, l = tid & 63, fr = l & 15, fo = l >> 4;
    int cpos = w & 3, gate = w >> 2;
    int fr8 = fr & 7;

    // whh A-fragments -> registers, once
    bf16x8 a[16];
    {
        const u16* wp = whhT + ((size_t)(gate << 9) + cbase + cpos * 16 + fr) * 512 + fo * 8;
#pragma unroll
        for (int kk = 0; kk < 16; ++kk)
            a[kk] = *(const bf16x8*)(wp + kk * 32);
    }

    // epilogue: threads 0..255 own (t = et, cols ec, ec+1) for BOTH chains
    int et = tid >> 5, ec = (tid & 31) * 2;
    bool ep = tid < 256;
    float hA0 = 0.f, hA1 = 0.f, hB0 = 0.f, hB1 = 0.f;
    float bh_r0 = 0, bh_r1 = 0, bh_z0 = 0, bh_z1 = 0, bh_n0 = 0, bh_n1 = 0;
    if (ep) {
        bh_r0 = bhh[cbase + ec];        bh_r1 = bhh[cbase + ec + 1];
        bh_z0 = bhh[512 + cbase + ec];  bh_z1 = bhh[512 + cbase + ec + 1];
        bh_n0 = bhh[1024 + cbase + ec]; bh_n1 = bhh[1024 + cbase + ec + 1];
    }

    const unsigned* gp = (const unsigned*)gi_bf;
    const u64* h0q = (const u64*)h0_bf;
    u64* outq = (u64*)out_bf;

    // prologue: stage lhA with h0 rows tA..tA+7 (no poll needed: h0 ready)
    {
        int r = tid >> 7, kw = tid & 127;
        if (tid < 1024)
            lhA[r * 128 + (kw ^ (r << 1))] =
                h0q[(size_t)(tA + r) * 64 + kw] * 0 +    // h0 is zeros; keep read for generality
                __hip_atomic_load(h0q + (size_t)(tA + r) * 64 + kw,
                                  __ATOMIC_RELAXED, __HIP_MEMORY_SCOPE_AGENT) * 0;
        // h0q rows are 512 bf16 = 128 u64; index = row*128 + kw
        if (tid < 1024)
            lhA[r * 128 + (kw ^ (r << 1))] =
                __hip_atomic_load(h0q + (size_t)(tA + r) * 128 + kw,
                                  __ATOMIC_RELAXED, __HIP_MEMORY_SCOPE_AGENT);
        int tid2 = tid + 768;
        if (tid2 < 1024) {
            int r2 = tid2 >> 7, kw2 = tid2 & 127;
            lhA[r2 * 128 + (kw2 ^ (r2 << 1))] =
                __hip_atomic_load(h0q + (size_t)(tA + r2) * 128 + kw2,
                                  __ATOMIC_RELAXED, __HIP_MEMORY_SCOPE_AGENT);
        }
    }

    int fslot_own = (p * 8 + cb) * 16;
    int fslot_peer = (p * 8 + (tid & 7)) * 16;

    for (int s = 0; s < 64; ++s) {
        // ================= X gate: publish B(s-1) done; poll B peers =======
        if (tid == 0)
            __hip_atomic_store(&flagsB[fslot_own], (unsigned)s,
                               __ATOMIC_RELAXED, __HIP_MEMORY_SCOPE_AGENT);
        if (tid < 8) {
            while (__hip_atomic_load(&flagsB[fslot_peer],
                                     __ATOMIC_RELAXED, __HIP_MEMORY_SCOPE_AGENT) < (unsigned)s)
                __builtin_amdgcn_s_sleep(1);
        }
        __syncthreads();   // G1

        // ================= X.a: issue B loads + gi_A; MFMA A ===============
        const u64* hbB = s ? outq + (size_t)((s - 1) * 512) * 64 : h0q;
        // rows of hbB are 512 bf16 = 64?? (u64 = 4 bf16 -> 128 u64/row)
        const u64* srcB = s ? outq + ((size_t)(s - 1) * 512 + tB) * 128 : h0q + (size_t)tB * 128;
        u64 rB0, rB1 = 0;
        {
            int r = tid >> 7, kw = tid & 127;
            rB0 = __hip_atomic_load(srcB + (size_t)r * 128 + kw,
                                    __ATOMIC_RELAXED, __HIP_MEMORY_SCOPE_AGENT);
            if (tid < 256) {
                int t2 = tid + 768;
                int r2 = t2 >> 7, kw2 = t2 & 127;
                rB1 = __hip_atomic_load(srcB + (size_t)r2 * 128 + kw2,
                                        __ATOMIC_RELAXED, __HIP_MEMORY_SCOPE_AGENT);
            }
        }
        unsigned gAr = 0, gAz = 0, gAn = 0;
        if (ep) {
            size_t grow = ((size_t)s * 512 + tA + et) * 1536;
            gAr = gp[(grow + cbase + ec) >> 1];
            gAz = gp[(grow + 512 + cbase + ec) >> 1];
            gAn = gp[(grow + 1024 + cbase + ec) >> 1];
        }
        {
            f32x4 acc = {0.f, 0.f, 0.f, 0.f};
#pragma unroll
            for (int kk = 0; kk < 16; ++kk) {
                int kb = kk * 32 + fo * 8;
                bf16x8 b = *(bf16x8*)&lA16[fr8 * 512 + (kb ^ (fr8 << 3))];
                acc = __builtin_amdgcn_mfma_f32_16x16x32_bf16(a[kk], b, acc, 0, 0, 0);
            }
            if (fr < 8) *(f32x4*)&ghs[gate][fr][cpos * 16 + fo * 4] = acc;
        }
        {   // commit rB -> lhB (swizzled)
            int r = tid >> 7, kw = tid & 127;
            lhB[r * 128 + (kw ^ (r << 1))] = rB0;
            if (tid < 256) {
                int t2 = tid + 768;
                int r2 = t2 >> 7, kw2 = t2 & 127;
                lhB[r2 * 128 + (kw2 ^ (r2 << 1))] = rB1;
            }
        }
        __syncthreads();   // G2

        // ================= X.b: gates A + store h_A(s) =====================
        if (ep) {
            float ghr0 = ghs[0][et][ec], ghr1 = ghs[0][et][ec + 1];
            float ghz0 = ghs[1][et][ec], ghz1 = ghs[1][et][ec + 1];
            float ghn0 = ghs[2][et][ec], ghn1 = ghs[2][et][ec + 1];
            float r0 = sigmoidf_(bf2f((u16)(gAr & 0xffff)) + ghr0 + bh_r0);
            float r1 = sigmoidf_(bf2f((u16)(gAr >> 16)) + ghr1 + bh_r1);
            float z0 = sigmoidf_(bf2f((u16)(gAz & 0xffff)) + ghz0 + bh_z0);
            float z1 = sigmoidf_(bf2f((u16)(gAz >> 16)) + ghz1 + bh_z1);
            float n0 = tanhf(bf2f((u16)(gAn & 0xffff)) + r0 * (ghn0 + bh_n0));
            float n1 = tanhf(bf2f((u16)(gAn >> 16)) + r1 * (ghn1 + bh_n1));
            hA0 = (1.f - z0) * n0 + z0 * hA0;
            hA1 = (1.f - z1) * n1 + z1 * hA1;
            unsigned packv = (unsigned)f2bf(hA0) | ((unsigned)f2bf(hA1) << 16);
            __hip_atomic_store(
                (unsigned*)out_bf + ((((size_t)s * 512 + tA + et) * 512 + cbase + ec) >> 1),
                packv, __ATOMIC_RELAXED, __HIP_MEMORY_SCOPE_AGENT);
        }
        __syncthreads();   // G3 (drains h_A stores)

        // ================= Y gate: publish A(s) done; poll A peers =========
        if (tid == 0)
            __hip_atomic_store(&flagsA[fslot_own], (unsigned)(s + 1),
                               __ATOMIC_RELAXED, __HIP_MEMORY_SCOPE_AGENT);
        if (tid < 8) {
            while (__hip_atomic_load(&flagsA[fslot_peer],
                                     __ATOMIC_RELAXED, __HIP_MEMORY_SCOPE_AGENT) < (unsigned)(s + 1))
                __builtin_amdgcn_s_sleep(1);
        }
        __syncthreads();   // G4

        // ================= Y.a: issue A(s+1) loads + gi_B; MFMA B ==========
        const u64* srcA = outq + ((size_t)s * 512 + tA) * 128;
        u64 rA0, rA1 = 0;
        {
            int r = tid >> 7, kw = tid & 127;
            rA0 = __hip_atomic_load(srcA + (size_t)r * 128 + kw,
                                    __ATOMIC_RELAXED, __HIP_MEMORY_SCOPE_AGENT);
            if (tid < 256) {
                int t2 = tid + 768;
                int r2 = t2 >> 7, kw2 = t2 & 127;
                rA1 = __hip_atomic_load(srcA + (size_t)r2 * 128 + kw2,
                                        __ATOMIC_RELAXED, __HIP_MEMORY_SCOPE_AGENT);
            }
        }
        unsigned gBr = 0, gBz = 0, gBn = 0;
        if (ep) {
            size_t grow = ((size_t)s * 512 + tB + et) * 1536;
            gBr = gp[(grow + cbase + ec) >> 1];
            gBz = gp[(grow + 512 + cbase + ec) >> 1];
            gBn = gp[(grow + 1024 + cbase + ec) >> 1];
        }
        {
            f32x4 acc = {0.f, 0.f, 0.f, 0.f};
#pragma unroll
            for (int kk = 0; kk < 16; ++kk) {
                int kb = kk * 32 + fo * 8;
                bf16x8 b = *(bf16x8*)&lB16[fr8 * 512 + (kb ^ (fr8 << 3))];
                acc = __builtin_amdgcn_mfma_f32_16x16x32_bf16(a[kk], b, acc, 0, 0, 0);
            }
            if (fr < 8) *(f32x4*)&ghs[gate][fr][cpos * 16 + fo * 4] = acc;
        }
        {   // commit rA -> lhA (input for A step s+1)
            int r = tid >> 7, kw = tid & 127;
            lhA[r * 128 + (kw ^ (r << 1))] = rA0;
            if (tid < 256) {
                int t2 = tid + 768;
                int r2 = t2 >> 7, kw2 = t2 & 127;
                lhA[r2 * 128 + (kw2 ^ (r2 << 1))] = rA1;
            }
        }
        __syncthreads();   // G5

        // ================= Y.b: gates B + store h_B(s) =====================
        if (ep) {
            float ghr0 = ghs[0][et][ec], ghr1 = ghs[0][et][ec + 1];
            float ghz0 = ghs[1][et][ec], ghz1 = ghs[1][et][ec + 1];
            float ghn0 = ghs[2][et][ec], ghn1 = ghs[2][et][ec + 1];
            float r0 = sigmoidf_(bf2f((u16)(gBr & 0xffff)) + ghr0 + bh_r0);
            float r1 = sigmoidf_(bf2f((u16)(gBr >> 16)) + ghr1 + bh_r1);
            float z0 = sigmoidf_(bf2f((u16)(gBz & 0xffff)) + ghz0 + bh_z0);
            float z1 = sigmoidf_(bf2f((u16)(gBz >> 16)) + ghz1 + bh_z1);
            float n0 = tanhf(bf2f((u16)(gBn & 0xffff)) + r0 * (ghn0 + bh_n0));
            float n1 = tanhf(bf2f((u16)(gBn >> 16)) + r1 * (ghn1 + bh_n1));
            hB0 = (1.f - z0) * n0 + z0 * hB0;
            hB1 = (1.f - z1) * n1 + z1 * hB1;
            unsigned packv = (unsigned)f2bf(hB0) | ((unsigned)f2bf(hB1) << 16);
            __hip_atomic_store(
                (unsigned*)out_bf + ((((size_t)s * 512 + tB + et) * 512 + cbase + ec) >> 1),
                packv, __ATOMIC_RELAXED, __HIP_MEMORY_SCOPE_AGENT);
        }
        __syncthreads();   // G6 (drains h_B stores)
    }
}

// ---------------------------------------------------------------------------
extern "C" void kernel_launch(void* const* d_in, const int* in_sizes, int n_in,
                              void* d_out, int out_size, void* d_ws, size_t ws_size,
                              hipStream_t stream)
{
    const float* state   = (const float*)d_in[0];
    const float* action  = (const float*)d_in[1];
    const float* ae_w1   = (const float*)d_in[2];
    const float* ae_b1   = (const float*)d_in[3];
    const float* ae_w2   = (const float*)d_in[4];
    const float* ae_b2   = (const float*)d_in[5];
    const float* ln2_g   = (const float*)d_in[8];
    const float* ln2_b   = (const float*)d_in[9];
    const float* wv      = (const float*)d_in[14];
    const float* bv      = (const float*)d_in[15];
    const float* wo      = (const float*)d_in[16];
    const float* bo      = (const float*)d_in[17];
    const float* gru_wih = (const float*)d_in[18];
    const float* gru_bih = (const float*)d_in[19];
    const float* gru_whh = (const float*)d_in[20];
    const float* gru_bhh = (const float*)d_in[21];
    const float* mlp_w   = (const float*)d_in[22];
    const float* mlp_b   = (const float*)d_in[23];

    char* ws = (char*)d_ws;
    size_t off = 0;
    auto carve = [&](size_t bytes) -> char* {
        char* p = ws + off; off = (off + bytes + 255) & ~(size_t)255; return p;
    };
    u16*   kv_bf  = (u16*)carve(32768ull * 256 * 2);
    u16*   x_bf   = (u16*)carve(32768ull * 256 * 2);
    u16*   gi_bf  = (u16*)carve(32768ull * 1536 * 2);
    u16*   out_bf = (u16*)carve(32768ull * 512 * 2);
    u16*   WfT    = (u16*)carve(256 * 256 * 2);
    float* bfv    = (float*)carve(256 * 4);
    u16*   wihT   = (u16*)carve(1536 * 256 * 2);
    u16*   whhT   = (u16*)carve(1536 * 512 * 2);
    u16*   mlpT   = (u16*)carve(256 * 512 * 2);
    u16*   w2T    = (u16*)carve(256 * 128 * 2);
    u16*   h0_bf  = (u16*)carve(512 * 512 * 2);
    unsigned* flagsA = (unsigned*)carve(256 * 16 * 4);
    unsigned* flagsB = (unsigned*)carve(256 * 16 * 4);

    hipMemsetAsync(h0_bf, 0, 512 * 512 * 2, stream);
    hipMemsetAsync(flagsA, 0, 256 * 16 * 4, stream);
    hipMemsetAsync(flagsB, 0, 256 * 16 * 4, stream);

    fuse_wvwo<<<256, 256, 0, stream>>>(wv, wo, bv, bo, WfT, bfv);
    transpose_bf<<<1536, 256, 0, stream>>>(gru_wih, wihT, 256, 1536);
    transpose_bf<<<3072, 256, 0, stream>>>(gru_whh, whhT, 512, 1536);
    transpose_bf<<<512, 256, 0, stream>>>(mlp_w, mlpT, 512, 256);
    transpose_bf<<<128, 256, 0, stream>>>(ae_w2, w2T, 128, 256);

    ae_ln_mfma<<<512, 256, 0, stream>>>(action, ae_w1, ae_b1, w2T, ae_b2,
                                        ln2_g, ln2_b, kv_bf);

    // x = state + kv_in @ Wf + bfv   (bf16 out)
    gemm128<0><<<dim3(256, 2), 256, 0, stream>>>(kv_bf, WfT, bfv, state, x_bf, nullptr, 256, 256);
    // gi = x @ wih + bih             (bf16 out)
    gemm128<1><<<dim3(256, 12), 256, 0, stream>>>(x_bf, wihT, gru_bih, nullptr, gi_bf, nullptr, 1536, 256);

    // GRU: one persistent cooperative kernel, two-chain antiphase pipeline
    {
        void* args[] = { (void*)&whhT, (void*)&gru_bhh, (void*)&gi_bf,
                         (void*)&h0_bf, (void*)&out_bf, (void*)&flagsA, (void*)&flagsB };
        hipError_t cerr = hipLaunchCooperativeKernel((const void*)gru_persistent7,
                                                     dim3(256), dim3(768), args, 0, stream);
        if (cerr != hipSuccess) {
            gru_persistent7<<<dim3(256), dim3(768), 0, stream>>>(
                whhT, gru_bhh, gi_bf, h0_bf, out_bf, flagsA, flagsB);
        }
    }

    // states = out @ mlp_w + mlp_b   (f32 out + last-row duplicate)
    gemm128<2><<<dim3(256, 2), 256, 0, stream>>>(out_bf, mlpT, mlp_b, nullptr, nullptr,
                                                 (float*)d_out, 256, 512);
}

// Round 10
// 395.303 us; speedup vs baseline: 1.2456x; 1.2456x over previous
//
#include <hip/hip_runtime.h>
#include <hip/hip_bf16.h>

typedef unsigned short u16;
typedef unsigned long long u64;
typedef __attribute__((ext_vector_type(8))) short bf16x8;
typedef __attribute__((ext_vector_type(4))) float f32x4;

static __device__ __forceinline__ u16 f2bf(float f) {
    union { float f; unsigned u; } cv; cv.f = f;
    unsigned u = cv.u;
    unsigned r = u + 0x7FFF + ((u >> 16) & 1);   // round-to-nearest-even
    return (u16)(r >> 16);
}
static __device__ __forceinline__ float bf2f(u16 b) {
    union { unsigned u; float f; } cv; cv.u = ((unsigned)b) << 16;
    return cv.f;
}
static __device__ __forceinline__ float sigmoidf_(float x) {
    return 1.0f / (1.0f + __expf(-x));
}

// ---------------------------------------------------------------------------
// Coalesced tiled transpose-convert: dst[n*K + k] = bf16(src[k*N + n]).
// Grid (K/64, N/64), 256 threads.
__global__ __launch_bounds__(256) void transpose_tile_bf(
    const float* __restrict__ src, u16* __restrict__ dst, int K, int N)
{
    __shared__ u16 t[64][66];
    int k0 = blockIdx.x * 64, n0 = blockIdx.y * 64;
    int tid = threadIdx.x;
    int r = tid >> 4, c4 = (tid & 15) * 4;
#pragma unroll
    for (int p = 0; p < 4; ++p) {
        int row = r + p * 16;
        float4 v = *(const float4*)&src[(size_t)(k0 + row) * N + n0 + c4];
        t[c4 + 0][row] = f2bf(v.x);
        t[c4 + 1][row] = f2bf(v.y);
        t[c4 + 2][row] = f2bf(v.z);
        t[c4 + 3][row] = f2bf(v.w);
    }
    __syncthreads();
    int rr = tid >> 3, cc = (tid & 7) * 8;
#pragma unroll
    for (int p = 0; p < 2; ++p) {
        int row = rr + p * 32;
        u16 pack[8];
#pragma unroll
        for (int j = 0; j < 8; ++j) pack[j] = t[row][cc + j];
        *(uint4*)&dst[(size_t)(n0 + row) * K + k0 + cc] = *(uint4*)pack;
    }
}

// row-major f32 -> bf16 convert (n multiple of 1024)
__global__ __launch_bounds__(256) void convert_bf(
    const float* __restrict__ src, u16* __restrict__ dst)
{
    int i = (blockIdx.x * 256 + threadIdx.x) * 4;
    float4 v = *(const float4*)&src[i];
    u16 pack[4] = { f2bf(v.x), f2bf(v.y), f2bf(v.z), f2bf(v.w) };
    *(u64*)&dst[i] = *(u64*)pack;
}

// bfv[j] = bo[j] + sum_k bv[k] * wo[k*256+j]   (coalesced over j)
__global__ __launch_bounds__(256) void bias_fuse(
    const float* __restrict__ bv, const float* __restrict__ wo,
    const float* __restrict__ bo, float* __restrict__ bfv)
{
    int j = threadIdx.x;
    float t = bo[j];
    for (int k = 0; k < 256; ++k) t = fmaf(bv[k], wo[k * 256 + j], t);
    bfv[j] = t;
}

// ---------------------------------------------------------------------------
// Fused action-encoder + LayerNorm, MFMA version. 64 positions per block.
__global__ __launch_bounds__(256) void ae_ln_mfma(
    const float* __restrict__ action,
    const float* __restrict__ w1, const float* __restrict__ b1,
    const u16* __restrict__ w2T, const float* __restrict__ b2,
    const float* __restrict__ g, const float* __restrict__ be,
    u16* __restrict__ kvbf)
{
    __shared__ u16 lB[256][136];   // w2T staged; reused as f32 [64][261] later
    __shared__ u16 lA[64][136];    // h1 tile bf16
    int tid = threadIdx.x;
    long base = (long)blockIdx.x * 64;

    for (int idx = tid; idx < 256 * 16; idx += 256) {
        int r = idx >> 4, ch = (idx & 15) * 8;
        *(uint4*)&lB[r][ch] = *(const uint4*)&w2T[r * 128 + ch];
    }
    for (int idx = tid; idx < 8192; idx += 256) {
        int r = idx >> 7, k = idx & 127;
        float a0 = action[(base + r) * 2], a1 = action[(base + r) * 2 + 1];
        float v = fmaf(a1, w1[128 + k], fmaf(a0, w1[k], b1[k]));
        lA[r][k] = f2bf(v > 0.f ? v : 0.f);
    }
    __syncthreads();

    int wv = tid >> 6, l = tid & 63;
    int fr = l & 15, fq = l >> 4;
    f32x4 acc[4][4] = {};
#pragma unroll
    for (int ks = 0; ks < 4; ++ks) {
        bf16x8 a[4], b[4];
#pragma unroll
        for (int mi = 0; mi < 4; ++mi) a[mi] = *(bf16x8*)&lA[mi * 16 + fr][ks * 32 + fq * 8];
#pragma unroll
        for (int ni = 0; ni < 4; ++ni) b[ni] = *(bf16x8*)&lB[wv * 64 + ni * 16 + fr][ks * 32 + fq * 8];
#pragma unroll
        for (int mi = 0; mi < 4; ++mi)
#pragma unroll
            for (int ni = 0; ni < 4; ++ni)
                acc[mi][ni] = __builtin_amdgcn_mfma_f32_16x16x32_bf16(a[mi], b[ni], acc[mi][ni], 0, 0, 0);
    }
    __syncthreads();

    float* e = (float*)&lB[0][0];   // [64][261] f32 scratch
#pragma unroll
    for (int mi = 0; mi < 4; ++mi)
#pragma unroll
        for (int ni = 0; ni < 4; ++ni) {
            int col = wv * 64 + ni * 16 + fr;
            float bb = b2[col];
#pragma unroll
            for (int reg = 0; reg < 4; ++reg)
                e[(mi * 16 + fq * 4 + reg) * 261 + col] = acc[mi][ni][reg] + bb;
        }
    __syncthreads();

    int t = tid >> 2, sub = tid & 3;
    float s = 0.f, ss = 0.f;
#pragma unroll
    for (int i = 0; i < 64; ++i) {
        float v = e[t * 261 + sub + i * 4];
        s += v; ss += v * v;
    }
    s += __shfl_xor(s, 1); ss += __shfl_xor(ss, 1);
    s += __shfl_xor(s, 2); ss += __shfl_xor(ss, 2);
    float m = s * (1.f / 256.f);
    float var = ss * (1.f / 256.f) - m * m;
    float rs = rsqrtf(var + 1e-5f);
#pragma unroll
    for (int i8 = 0; i8 < 8; ++i8) {
        u16 pack[8];
#pragma unroll
        for (int j = 0; j < 8; ++j) {
            int col = sub * 64 + i8 * 8 + j;
            float v = (e[t * 261 + col] - m) * rs * g[col] + be[col];
            pack[j] = f2bf(v);
        }
        *(uint4*)&kvbf[(base + t) * 256 + sub * 64 + i8 * 8] = *(uint4*)pack;
    }
}

// ---------------------------------------------------------------------------
// 128x128-tile bf16 GEMM, BK=64: C = A[M,K] @ BT[N,K]^T (+bias[col]) (+modes)
template <int MODE>
__global__ __launch_bounds__(256) void gemm128(
    const u16* __restrict__ A, const u16* __restrict__ BT,
    const float* __restrict__ bias, const float* __restrict__ resid,
    u16* __restrict__ outBf, float* __restrict__ outF,
    int N, int K)
{
    __shared__ u16 lA[128][72];
    __shared__ u16 lB[128][72];
    int tid = threadIdx.x;
    int bm = blockIdx.x * 128, bn = blockIdx.y * 128;

    f32x4 acc[4][4] = {};
    int w = tid >> 6, l = tid & 63;
    int wr = (w >> 1) * 64, wc = (w & 1) * 64;
    int fr = l & 15, fk = (l >> 4) * 8;

    for (int k0 = 0; k0 < K; k0 += 64) {
#pragma unroll
        for (int i = 0; i < 4; ++i) {
            int idx = tid + i * 256;
            int r = idx >> 3, c8 = (idx & 7) * 8;
            *(uint4*)&lA[r][c8] = *(const uint4*)&A[(long)(bm + r) * K + k0 + c8];
            *(uint4*)&lB[r][c8] = *(const uint4*)&BT[(long)(bn + r) * K + k0 + c8];
        }
        __syncthreads();
#pragma unroll
        for (int half = 0; half < 2; ++half) {
            int fo = half * 32 + fk;
            bf16x8 a[4], b[4];
#pragma unroll
            for (int mi = 0; mi < 4; ++mi) a[mi] = *(bf16x8*)&lA[wr + mi * 16 + fr][fo];
#pragma unroll
            for (int ni = 0; ni < 4; ++ni) b[ni] = *(bf16x8*)&lB[wc + ni * 16 + fr][fo];
#pragma unroll
            for (int mi = 0; mi < 4; ++mi)
#pragma unroll
                for (int ni = 0; ni < 4; ++ni)
                    acc[mi][ni] = __builtin_amdgcn_mfma_f32_16x16x32_bf16(a[mi], b[ni], acc[mi][ni], 0, 0, 0);
        }
        __syncthreads();
    }

#pragma unroll
    for (int mi = 0; mi < 4; ++mi)
#pragma unroll
        for (int ni = 0; ni < 4; ++ni) {
            int c = bn + wc + ni * 16 + fr;
            float bz = bias[c];
#pragma unroll
            for (int reg = 0; reg < 4; ++reg) {
                int r = bm + wr + mi * 16 + (l >> 4) * 4 + reg;
                float v = acc[mi][ni][reg] + bz;
                if constexpr (MODE == 0) {
                    v += resid[(long)r * N + c];
                    outBf[(long)r * N + c] = f2bf(v);
                } else if constexpr (MODE == 1) {
                    outBf[(long)r * N + c] = f2bf(v);
                } else {
                    outF[(long)r * N + c] = v;
                    if ((r & 511) == 511) outF[8388608 + (long)(r >> 9) * N + c] = v;
                }
            }
        }
}

// ---------------------------------------------------------------------------
// Persistent GRU v6 (reverted known-good). 256 blocks = 32 t-groups x 8
// col-blocks (64 cols each), 768 threads = 12 waves = (cpos 0..3, gate 0..2).
__global__ __launch_bounds__(768, 1) void gru_persistent6(
    const u16* __restrict__ whhT, const float* __restrict__ bhh,
    const u16* __restrict__ gi_bf, const u16* __restrict__ h0_bf,
    u16* __restrict__ out_bf, unsigned* __restrict__ flags)
{
    __shared__ u64 lh64[2048];                       // swizzled h [16][512] bf16
    __shared__ __align__(16) float ghs[3][16][68];   // [gate][t_loc][c_loc]
    u16* lh = (u16*)lh64;

    int tid = threadIdx.x;
    int bid = blockIdx.x;
    int tg = bid >> 3, cb = bid & 7;
    int tbase = tg * 16, cbase = cb * 64;

    int w = tid >> 6, l = tid & 63;
    int fr = l & 15, fo = l >> 4;
    int cpos = w & 3, gate = w >> 2;

    bf16x8 a[16];
    {
        const u16* wp = whhT + ((size_t)(gate << 9) + cbase + cpos * 16 + fr) * 512 + fo * 8;
#pragma unroll
        for (int kk = 0; kk < 16; ++kk)
            a[kk] = *(const bf16x8*)(wp + kk * 32);
    }

    int et = tid >> 5, ec = (tid & 31) * 2;
    bool ep = tid < 512;
    float hreg0 = 0.f, hreg1 = 0.f;
    float bh_r0 = 0, bh_r1 = 0, bh_z0 = 0, bh_z1 = 0, bh_n0 = 0, bh_n1 = 0;
    if (ep) {
        bh_r0 = bhh[cbase + ec];        bh_r1 = bhh[cbase + ec + 1];
        bh_z0 = bhh[512 + cbase + ec];  bh_z1 = bhh[512 + cbase + ec + 1];
        bh_n0 = bhh[1024 + cbase + ec]; bh_n1 = bhh[1024 + cbase + ec + 1];
    }

    const unsigned* gp = (const unsigned*)gi_bf;
    unsigned g_r = 0, g_z = 0, g_n = 0;
    if (ep) {
        size_t grow = (size_t)(tbase + et) * 1536;
        g_r = gp[(grow + cbase + ec) >> 1];
        g_z = gp[(grow + 512 + cbase + ec) >> 1];
        g_n = gp[(grow + 1024 + cbase + ec) >> 1];
    }

    for (int step = 0; step < 64; ++step) {
        const u64* hb64 = (const u64*)(step ? out_bf + (size_t)(step - 1) * 262144
                                           : h0_bf);
#pragma unroll
        for (int i = 0; i < 3; ++i) {
            int idx = tid + i * 768;
            if (idx < 2048) {
                int r = idx >> 7, kw = idx & 127;
                u64 v = __hip_atomic_load(hb64 + (size_t)(tbase + r) * 128 + kw,
                                          __ATOMIC_RELAXED, __HIP_MEMORY_SCOPE_AGENT);
                lh64[r * 128 + (kw ^ ((r & 7) << 1))] = v;
            }
        }
        __syncthreads();

        f32x4 acc = {0.f, 0.f, 0.f, 0.f};
#pragma unroll
        for (int kk = 0; kk < 16; ++kk) {
            int kb = kk * 32 + fo * 8;
            bf16x8 b = *(bf16x8*)&lh[fr * 512 + (kb ^ ((fr & 7) << 3))];
            acc = __builtin_amdgcn_mfma_f32_16x16x32_bf16(a[kk], b, acc, 0, 0, 0);
        }
        *(f32x4*)&ghs[gate][fr][cpos * 16 + fo * 4] = acc;
        __syncthreads();

        if (ep) {
            float ghr0 = ghs[0][et][ec], ghr1 = ghs[0][et][ec + 1];
            float ghz0 = ghs[1][et][ec], ghz1 = ghs[1][et][ec + 1];
            float ghn0 = ghs[2][et][ec], ghn1 = ghs[2][et][ec + 1];
            float r0 = sigmoidf_(bf2f((u16)(g_r & 0xffff)) + ghr0 + bh_r0);
            float r1 = sigmoidf_(bf2f((u16)(g_r >> 16)) + ghr1 + bh_r1);
            float z0 = sigmoidf_(bf2f((u16)(g_z & 0xffff)) + ghz0 + bh_z0);
            float z1 = sigmoidf_(bf2f((u16)(g_z >> 16)) + ghz1 + bh_z1);
            float n0 = tanhf(bf2f((u16)(g_n & 0xffff)) + r0 * (ghn0 + bh_n0));
            float n1 = tanhf(bf2f((u16)(g_n >> 16)) + r1 * (ghn1 + bh_n1));
            hreg0 = (1.f - z0) * n0 + z0 * hreg0;
            hreg1 = (1.f - z1) * n1 + z1 * hreg1;
            unsigned packv = (unsigned)f2bf(hreg0) | ((unsigned)f2bf(hreg1) << 16);
            __hip_atomic_store(
                (unsigned*)out_bf + ((((size_t)step * 512 + tbase + et) * 512 + cbase + ec) >> 1),
                packv, __ATOMIC_RELAXED, __HIP_MEMORY_SCOPE_AGENT);
        }
        __syncthreads();

        if (step < 63) {
            if (tid == 0)
                __hip_atomic_store(&flags[(tg * 8 + cb) * 32], (unsigned)(step + 1),
                                   __ATOMIC_RELAXED, __HIP_MEMORY_SCOPE_AGENT);
            if (ep) {
                size_t grow = ((size_t)(step + 1) * 512 + tbase + et) * 1536;
                g_r = gp[(grow + cbase + ec) >> 1];
                g_z = gp[(grow + 512 + cbase + ec) >> 1];
                g_n = gp[(grow + 1024 + cbase + ec) >> 1];
            }
            if (tid < 8) {
                unsigned tgt = (unsigned)(step + 1);
                while (__hip_atomic_load(&flags[(tg * 8 + tid) * 32],
                                         __ATOMIC_RELAXED, __HIP_MEMORY_SCOPE_AGENT) < tgt)
                    __builtin_amdgcn_s_sleep(1);
            }
            __syncthreads();
        }
    }
}

// ---------------------------------------------------------------------------
extern "C" void kernel_launch(void* const* d_in, const int* in_sizes, int n_in,
                              void* d_out, int out_size, void* d_ws, size_t ws_size,
                              hipStream_t stream)
{
    const float* state   = (const float*)d_in[0];
    const float* action  = (const float*)d_in[1];
    const float* ae_w1   = (const float*)d_in[2];
    const float* ae_b1   = (const float*)d_in[3];
    const float* ae_w2   = (const float*)d_in[4];
    const float* ae_b2   = (const float*)d_in[5];
    const float* ln2_g   = (const float*)d_in[8];
    const float* ln2_b   = (const float*)d_in[9];
    const float* wv      = (const float*)d_in[14];
    const float* bv      = (const float*)d_in[15];
    const float* wo      = (const float*)d_in[16];
    const float* bo      = (const float*)d_in[17];
    const float* gru_wih = (const float*)d_in[18];
    const float* gru_bih = (const float*)d_in[19];
    const float* gru_whh = (const float*)d_in[20];
    const float* gru_bhh = (const float*)d_in[21];
    const float* mlp_w   = (const float*)d_in[22];
    const float* mlp_b   = (const float*)d_in[23];

    char* ws = (char*)d_ws;
    size_t off = 0;
    auto carve = [&](size_t bytes) -> char* {
        char* p = ws + off; off = (off + bytes + 255) & ~(size_t)255; return p;
    };
    u16*   kv_bf  = (u16*)carve(32768ull * 256 * 2);
    u16*   x_bf   = (u16*)carve(32768ull * 256 * 2);
    u16*   gi_bf  = (u16*)carve(32768ull * 1536 * 2);
    u16*   out_bf = (u16*)carve(32768ull * 512 * 2);
    u16*   WfT    = (u16*)carve(256 * 256 * 2);
    float* bfv    = (float*)carve(256 * 4);
    u16*   wihT   = (u16*)carve(1536 * 256 * 2);
    u16*   whhT   = (u16*)carve(1536 * 512 * 2);
    u16*   mlpT   = (u16*)carve(256 * 512 * 2);
    u16*   w2T    = (u16*)carve(256 * 128 * 2);
    u16*   woT    = (u16*)carve(256 * 256 * 2);
    u16*   wv_bf  = (u16*)carve(256 * 256 * 2);
    float* zerob  = (float*)carve(256 * 4);
    u16*   h0_bf  = (u16*)carve(512 * 512 * 2);
    unsigned* flags = (unsigned*)carve(32 * 8 * 32 * 4);

    hipMemsetAsync(h0_bf, 0, 512 * 512 * 2, stream);
    hipMemsetAsync(flags, 0, 32 * 8 * 32 * 4, stream);
    hipMemsetAsync(zerob, 0, 256 * 4, stream);

    // weight preprocessing (all coalesced / tiled)
    convert_bf<<<64, 256, 0, stream>>>(wv, wv_bf);
    transpose_tile_bf<<<dim3(4, 4), 256, 0, stream>>>(wo, woT, 256, 256);
    transpose_tile_bf<<<dim3(4, 24), 256, 0, stream>>>(gru_wih, wihT, 256, 1536);
    transpose_tile_bf<<<dim3(8, 24), 256, 0, stream>>>(gru_whh, whhT, 512, 1536);
    transpose_tile_bf<<<dim3(8, 4), 256, 0, stream>>>(mlp_w, mlpT, 512, 256);
    transpose_tile_bf<<<dim3(2, 4), 256, 0, stream>>>(ae_w2, w2T, 128, 256);
    bias_fuse<<<1, 256, 0, stream>>>(bv, wo, bo, bfv);
    // WfT[j][i] = sum_k woT[j][k] * wv_bf[i][k]  (= (wv@wo)^T)
    gemm128<1><<<dim3(2, 2), 256, 0, stream>>>(woT, wv_bf, zerob, nullptr, WfT, nullptr, 256, 256);

    ae_ln_mfma<<<512, 256, 0, stream>>>(action, ae_w1, ae_b1, w2T, ae_b2,
                                        ln2_g, ln2_b, kv_bf);

    // x = state + kv_in @ Wf + bfv   (bf16 out)
    gemm128<0><<<dim3(256, 2), 256, 0, stream>>>(kv_bf, WfT, bfv, state, x_bf, nullptr, 256, 256);
    // gi = x @ wih + bih             (bf16 out)
    gemm128<1><<<dim3(256, 12), 256, 0, stream>>>(x_bf, wihT, gru_bih, nullptr, gi_bf, nullptr, 1536, 256);

    // GRU: one persistent cooperative kernel, all 64 steps
    {
        void* args[] = { (void*)&whhT, (void*)&gru_bhh, (void*)&gi_bf,
                         (void*)&h0_bf, (void*)&out_bf, (void*)&flags };
        hipError_t cerr = hipLaunchCooperativeKernel((const void*)gru_persistent6,
                                                     dim3(256), dim3(768), args, 0, stream);
        if (cerr != hipSuccess) {
            gru_persistent6<<<dim3(256), dim3(768), 0, stream>>>(
                whhT, gru_bhh, gi_bf, h0_bf, out_bf, flags);
        }
    }

    // states = out @ mlp_w + mlp_b   (f32 out + last-row duplicate)
    gemm128<2><<<dim3(256, 2), 256, 0, stream>>>(out_bf, mlpT, mlp_b, nullptr, nullptr,
                                                 (float*)d_out, 256, 512);
}